// Round 7
// baseline (1205.724 us; speedup 1.0000x reference)
//
#include <hip/hip_runtime.h>

#define N_NODES 100000
#define NREL 6
#define NEDGE 400000
#define FDIM 128
#define HID 128
#define CAP 24   // bucket slots per (relation,node); Poisson(4) max over 1.2M draws ~18
#define PADCAP (NEDGE + 3 * N_NODES)   // 700000: padded dense CSR capacity per relation

constexpr int RN = NREL * N_NODES;   // 600000
constexpr int RE = NREL * NEDGE;     // 2400000
constexpr int NB_SCAN = (N_NODES + 1023) / 1024;  // 98

// k_prep block-range dispatch
constexpr int NB_NS = (RN + 255) / 256;               // 2344
constexpr int NB_XC = (N_NODES * 32) / 256;           // 12500 (exact)
constexpr int NB_WC = (NREL * FDIM * HID) / 256;      // 384 (exact)
constexpr int PREP_BLOCKS = NB_NS + NB_XC + NB_WC + NREL + 1;

typedef __attribute__((ext_vector_type(8))) short short8;
typedef __attribute__((ext_vector_type(4))) float f32x4;

__device__ __forceinline__ unsigned short f2bf(float f) {
  union { float f; unsigned int u; } v; v.f = f;
  unsigned int u = v.u;
  unsigned int r = (u + 0x7FFFu + ((u >> 16) & 1u)) >> 16;
  return (unsigned short)r;
}
__device__ __forceinline__ float bflo(unsigned int w) {
  union { unsigned int u; float f; } v; v.u = w << 16; return v.f;
}
__device__ __forceinline__ float bfhi(unsigned int w) {
  union { unsigned int u; float f; } v; v.u = w & 0xffff0000u; return v.f;
}

// ---------------- zero workspace (uint4 stores) ----------------
__global__ void k_zero(uint4* __restrict__ p, int nq) {
  int id = blockIdx.x * blockDim.x + threadIdx.x;
  if (id < nq) p[id] = (uint4){0u, 0u, 0u, 0u};
}

// ---------------- single-pass build: in-buckets (by dst) + out-buckets (by src) ----------------
// cursor_in ends as deg_in; cursor_out ends as deg_out.
__global__ void k_build(const int4* __restrict__ src4, const int4* __restrict__ dst4,
                        int* __restrict__ cursor_in, int* __restrict__ cursor_out,
                        unsigned int* __restrict__ slots_in,
                        unsigned int* __restrict__ slots_out) {
  int id = blockIdx.x * 256 + threadIdx.x;
  if (id < RE / 4) {
    int r = id / (NEDGE / 4);
    int rN = r * N_NODES;
    int4 s = src4[id];
    int4 d = dst4[id];
    int p0 = atomicAdd(&cursor_in[rN + d.x], 1);
    int p1 = atomicAdd(&cursor_in[rN + d.y], 1);
    int p2 = atomicAdd(&cursor_in[rN + d.z], 1);
    int p3 = atomicAdd(&cursor_in[rN + d.w], 1);
    int q0 = atomicAdd(&cursor_out[rN + s.x], 1);
    int q1 = atomicAdd(&cursor_out[rN + s.y], 1);
    int q2 = atomicAdd(&cursor_out[rN + s.z], 1);
    int q3 = atomicAdd(&cursor_out[rN + s.w], 1);
    if (p0 < CAP) slots_in[(size_t)(rN + d.x) * CAP + p0] = (unsigned)s.x;
    if (p1 < CAP) slots_in[(size_t)(rN + d.y) * CAP + p1] = (unsigned)s.y;
    if (p2 < CAP) slots_in[(size_t)(rN + d.z) * CAP + p2] = (unsigned)s.z;
    if (p3 < CAP) slots_in[(size_t)(rN + d.w) * CAP + p3] = (unsigned)s.w;
    if (q0 < CAP) slots_out[(size_t)(rN + s.x) * CAP + q0] = (unsigned)d.x;
    if (q1 < CAP) slots_out[(size_t)(rN + s.y) * CAP + q1] = (unsigned)d.y;
    if (q2 < CAP) slots_out[(size_t)(rN + s.z) * CAP + q2] = (unsigned)d.z;
    if (q3 < CAP) slots_out[(size_t)(rN + s.w) * CAP + q3] = (unsigned)d.w;
  }
}

// ---------------- fused prep: ns,nd | x->bf16 | W1 transpose | u | biases ----------------
__global__ __launch_bounds__(256) void k_prep(
    const int* __restrict__ cursor_in, const int* __restrict__ cursor_out,
    float* __restrict__ ns, float* __restrict__ nd,
    const float* __restrict__ x, unsigned short* __restrict__ xb,
    const float* __restrict__ W1, const float* __restrict__ b1,
    const float* __restrict__ b2,
    unsigned short* __restrict__ W1T, float* __restrict__ bias1,
    float* __restrict__ bias2,
    const float* __restrict__ W2, const float* __restrict__ Wc,
    float* __restrict__ u) {
  const int b = blockIdx.x;
  const int t = threadIdx.x;
  if (b < NB_NS) {
    const int id = b * 256 + t;
    if (id < RN) {
      const int dO = cursor_out[id];
      ns[id] = dO > 0 ? rsqrtf((float)dO) : 0.f;
      int dI = cursor_in[id];
      dI = dI < CAP ? dI : CAP;
      nd[id] = dI > 0 ? rsqrtf((float)dI) : 0.f;
    }
  } else if (b < NB_NS + NB_XC) {
    const int id = (b - NB_NS) * 256 + t;
    const float4 v = ((const float4*)x)[id];
    ushort4 o;
    o.x = f2bf(v.x); o.y = f2bf(v.y); o.z = f2bf(v.z); o.w = f2bf(v.w);
    ((ushort4*)xb)[id] = o;
  } else if (b < NB_NS + NB_XC + NB_WC) {
    const int id = (b - NB_NS - NB_XC) * 256 + t;
    const int r = id >> 14;
    const int rem = id & 16383;
    const int j = rem >> 7;
    const int k = rem & 127;
    W1T[id] = f2bf(W1[r * 16384 + k * 128 + j]);
  } else if (b < NB_NS + NB_XC + NB_WC + NREL) {
    const int r = b - (NB_NS + NB_XC + NB_WC);
    const int k = t >> 1;
    const int c = t & 1;
    const float* __restrict__ row = W2 + r * (HID * HID) + k * HID;
    float s = 0.f;
#pragma unroll 8
    for (int j = 0; j < HID; ++j) s = fmaf(row[j], Wc[j * 2 + c], s);
    u[(r * HID + k) * 2 + c] = s;
  } else {
    if (t < HID) {
      float s1 = 0.f, s2 = 0.f;
      for (int r = 0; r < NREL; ++r) {
        s1 += b1[r * HID + t];
        s2 += b2[r * HID + t];
      }
      bias1[t] = s1;
      bias2[t] = s2;
    }
  }
}

// ---------------- scan stage 1: padded (clamped) in-degrees ----------------
__global__ __launch_bounds__(1024) void k_scan1(const int* __restrict__ cursor_in,
                                                int* __restrict__ csr_off,
                                                int* __restrict__ blockSums) {
  __shared__ int ws[16];
  const int r = blockIdx.x / NB_SCAN;
  const int b = blockIdx.x % NB_SCAN;
  const int t = threadIdx.x;
  const int wid = t >> 6;
  const int lane = t & 63;
  const int n = b * 1024 + t;
  int v = 0;
  if (n < N_NODES) {
    int d = cursor_in[r * N_NODES + n];
    d = d < CAP ? d : CAP;
    v = (d + 3) & ~3;
  }
  int sum = v;
#pragma unroll
  for (int off = 1; off < 64; off <<= 1) {
    int y = __shfl_up(sum, off);
    if (lane >= off) sum += y;
  }
  if (lane == 63) ws[wid] = sum;
  __syncthreads();
  if (wid == 0) {
    int s2 = (lane < 16) ? ws[lane] : 0;
#pragma unroll
    for (int off = 1; off < 16; off <<= 1) {
      int y = __shfl_up(s2, off);
      if (lane >= off) s2 += y;
    }
    if (lane < 16) ws[lane] = s2;
  }
  __syncthreads();
  if (wid > 0) sum += ws[wid - 1];
  if (n < N_NODES) csr_off[r * N_NODES + n] = sum - v;  // exclusive (within block)
  if (t == 1023) blockSums[blockIdx.x] = sum;
}

// ---------------- scan stage 2: exclusive scan of 98 block sums per relation ----------------
__global__ __launch_bounds__(768) void k_scan2(int* __restrict__ blockSums) {
  __shared__ int sh[NREL][128];
  const int t = threadIdx.x;
  const int r = t >> 7;
  const int b = t & 127;
  const int v = (b < NB_SCAN) ? blockSums[r * NB_SCAN + b] : 0;
  int cur = v;
  sh[r][b] = cur;
  __syncthreads();
  for (int off = 1; off < 128; off <<= 1) {
    int y = (b >= off) ? sh[r][b - off] : 0;
    __syncthreads();
    cur += y;
    sh[r][b] = cur;
    __syncthreads();
  }
  if (b < NB_SCAN) blockSums[r * NB_SCAN + b] = cur - v;  // exclusive
}

// ---------------- scan stage 3: meta = {deg_clamped, padded_off, nd_bits} ----------------
__global__ void k_scan3(const int* __restrict__ csr_off, const int* __restrict__ blockSums,
                        const int* __restrict__ cursor_in, int4* __restrict__ meta) {
  int id = blockIdx.x * 256 + threadIdx.x;
  if (id < RN) {
    int r = id / N_NODES;
    int n = id - r * N_NODES;
    const int off = csr_off[id] + blockSums[r * NB_SCAN + (n >> 10)];
    int d = cursor_in[id];
    d = d < CAP ? d : CAP;
    const float nd = d > 0 ? rsqrtf((float)d) : 0.f;
    meta[id] = make_int4(d, off, __float_as_int(nd), 0);
  }
}

// ---------------- compact: buckets -> dense padded CSR {src, ns[src]} ----------------
__global__ void k_compact(const unsigned int* __restrict__ slots_in,
                          const int4* __restrict__ meta,
                          const float* __restrict__ ns,
                          int2* __restrict__ csr_ew) {
  int id = blockIdx.x * 256 + threadIdx.x;
  if (id < RN) {
    const int r = id / N_NODES;
    const int rN = r * N_NODES;
    const int4 mt = meta[id];
    const int d = mt.x;
    if (d == 0) return;
    const unsigned int* __restrict__ bkt = slots_in + (size_t)id * CAP;
    int2* __restrict__ dst = csr_ew + (size_t)r * PADCAP + mt.y;
    const int nb = (d + 3) >> 2;
    for (int bi = 0; bi < nb; ++bi) {
      uint4 o0, o1;
      const int e = bi * 4;
      const unsigned s0 = bkt[e];
      const unsigned s1 = (e + 1 < d) ? bkt[e + 1] : 0u;
      const unsigned s2 = (e + 2 < d) ? bkt[e + 2] : 0u;
      const unsigned s3 = (e + 3 < d) ? bkt[e + 3] : 0u;
      o0.x = s0; o0.y = __float_as_uint(ns[rN + s0]);
      o0.z = s1; o0.w = (e + 1 < d) ? __float_as_uint(ns[rN + s1]) : 0u;
      o1.x = s2; o1.y = (e + 2 < d) ? __float_as_uint(ns[rN + s2]) : 0u;
      o1.z = s3; o1.w = (e + 3 < d) ? __float_as_uint(ns[rN + s3]) : 0u;
      *(uint4*)(dst + e) = o0;
      *(uint4*)(dst + e + 2) = o1;
    }
  }
}

// ---------------- fused layer-1: barrier-free waves, dense CSR, MFMA ----------------
__global__ __launch_bounds__(256, 6) void k_layer1(
    const unsigned short* __restrict__ xb,      // [N][128] bf16
    const int2* __restrict__ csr_ew,            // [R][PADCAP] {src, w}
    const int4* __restrict__ meta,              // [R][N] {d, off, nd_bits, -}
    const unsigned short* __restrict__ W1T,     // [R][128][128] bf16 (out, in)
    const float* __restrict__ bias1,
    unsigned short* __restrict__ h)             // [N][128] bf16
{
  __shared__ unsigned short zA[4][16][136];     // per-wave private slices
  const int tid = threadIdx.x;
  const int wave = tid >> 6;
  const int lane = tid & 63;
  const int sub = lane >> 4;        // 4 subs of 16 lanes
  const int flane = lane & 15;      // 8 bf16 features per lane
  const int wnb = blockIdx.x * 64 + wave * 16;  // this wave's 16 rows

  f32x4 acc[8];
#pragma unroll
  for (int t = 0; t < 8; ++t) acc[t] = (f32x4){0.f, 0.f, 0.f, 0.f};

  const int pn = wnb + flane;
  const bool pok = pn < N_NODES;
  const int pnc = pok ? pn : (N_NODES - 1);
  int4 mt = meta[pnc];
  if (!pok) { mt.x = 0; mt.z = 0; }

  for (int r = 0; r < NREL; ++r) {
    const int2* __restrict__ rel = csr_ew + (size_t)r * PADCAP;
    // ---- aggregation: 4 passes x 4 subs, no barriers (zA slice wave-private)
#pragma unroll
    for (int pass = 0; pass < 4; ++pass) {
      const int row = pass * 4 + sub;
      const int d = __shfl(mt.x, row);
      const int o = __shfl(mt.y, row);
      const float nd = __int_as_float(__shfl(mt.z, row));
      const uint4* __restrict__ lst = (const uint4*)(rel + o);
      const unsigned fo = (unsigned)(flane << 3);
      float b[8];
#pragma unroll
      for (int k = 0; k < 8; ++k) b[k] = 0.f;
      const int nb = (d + 3) >> 2;
      for (int bi = 0; bi < nb; ++bi) {
        const uint4 qa = lst[2 * bi];       // {s0,w0,s1,w1}
        const uint4 qb = lst[2 * bi + 1];   // {s2,w2,s3,w3}
        const float w0 = __uint_as_float(qa.y);
        const float w1 = __uint_as_float(qa.w);
        const float w2 = __uint_as_float(qb.y);
        const float w3 = __uint_as_float(qb.w);
        const uint4 v0 = *(const uint4*)(xb + ((size_t)qa.x << 7) + fo);
        const uint4 v1 = *(const uint4*)(xb + ((size_t)qa.z << 7) + fo);
        const uint4 v2 = *(const uint4*)(xb + ((size_t)qb.x << 7) + fo);
        const uint4 v3 = *(const uint4*)(xb + ((size_t)qb.z << 7) + fo);
#define ACC8(V, W) \
        b[0] = fmaf(bflo(V.x), W, b[0]); b[1] = fmaf(bfhi(V.x), W, b[1]); \
        b[2] = fmaf(bflo(V.y), W, b[2]); b[3] = fmaf(bfhi(V.y), W, b[3]); \
        b[4] = fmaf(bflo(V.z), W, b[4]); b[5] = fmaf(bfhi(V.z), W, b[5]); \
        b[6] = fmaf(bflo(V.w), W, b[6]); b[7] = fmaf(bfhi(V.w), W, b[7]);
        ACC8(v0, w0) ACC8(v1, w1) ACC8(v2, w2) ACC8(v3, w3)
#undef ACC8
      }
      uint4 pk;
      pk.x = (unsigned)f2bf(b[0] * nd) | ((unsigned)f2bf(b[1] * nd) << 16);
      pk.y = (unsigned)f2bf(b[2] * nd) | ((unsigned)f2bf(b[3] * nd) << 16);
      pk.z = (unsigned)f2bf(b[4] * nd) | ((unsigned)f2bf(b[5] * nd) << 16);
      pk.w = (unsigned)f2bf(b[6] * nd) | ((unsigned)f2bf(b[7] * nd) << 16);
      *(uint4*)(&zA[wave][row][flane * 8]) = pk;
    }
    // prefetch next relation's meta (hides under MFMA)
    int4 mtn = mt;
    if (r + 1 < NREL) {
      mtn = meta[(r + 1) * N_NODES + pnc];
      if (!pok) { mtn.x = 0; mtn.z = 0; }
    }
    // ---- MFMA: this wave's 16x128 A-tile x W^T -> acc
    const int m = lane & 15;
    const int qq = lane >> 4;
    const unsigned short* __restrict__ wr = W1T + r * (FDIM * HID);
#pragma unroll
    for (int kk = 0; kk < 4; ++kk) {
      const short8 af = *(const short8*)(&zA[wave][m][kk * 32 + qq * 8]);
#pragma unroll
      for (int t = 0; t < 8; ++t) {
        const short8 bfr = *(const short8*)(wr + (t * 16 + m) * 128 + kk * 32 + qq * 8);
        acc[t] = __builtin_amdgcn_mfma_f32_16x16x32_bf16(af, bfr, acc[t], 0, 0, 0);
      }
    }
    mt = mtn;
  }
  // ---- epilogue: bias + relu, store bf16
  const int col = lane & 15;
  const int rq = (lane >> 4) * 4;
#pragma unroll
  for (int t = 0; t < 8; ++t) {
#pragma unroll
    for (int rr = 0; rr < 4; ++rr) {
      const int node = wnb + rq + rr;
      if (node < N_NODES) {
        const int f = t * 16 + col;
        float v = acc[t][rr] + bias1[f];
        v = fmaxf(v, 0.f);
        h[(size_t)node * FDIM + f] = f2bf(v);
      }
    }
  }
}

// ---------------- layer-2 folded: single dense pass over h, coef from out-buckets ----------------
__global__ __launch_bounds__(256) void k_mv(
    const unsigned short* __restrict__ h,
    const unsigned int* __restrict__ slots_out,
    const int* __restrict__ cursor_out,
    const float* __restrict__ ns, const float* __restrict__ nd,
    float* __restrict__ mv) {
  __shared__ float sh[16][136];
  const int sub = threadIdx.x >> 4;
  const int flane = threadIdx.x & 15;
  const unsigned fo = (unsigned)(flane << 3);
  float acc[NREL][8];
#pragma unroll
  for (int r = 0; r < NREL; ++r)
#pragma unroll
    for (int k = 0; k < 8; ++k) acc[r][k] = 0.f;
  const int nbase = blockIdx.x * 256 + sub * 16;
  for (int i = 0; i < 16; ++i) {
    const int n = nbase + i;
    if (n >= N_NODES) break;
    const uint4 hv = *(const uint4*)(h + ((size_t)n << 7) + fo);
    float hf[8];
    hf[0] = bflo(hv.x); hf[1] = bfhi(hv.x); hf[2] = bflo(hv.y); hf[3] = bfhi(hv.y);
    hf[4] = bflo(hv.z); hf[5] = bfhi(hv.z); hf[6] = bflo(hv.w); hf[7] = bfhi(hv.w);
#pragma unroll
    for (int r = 0; r < NREL; ++r) {
      const int rn = r * N_NODES + n;
      int dO = cursor_out[rn];
      dO = dO < CAP ? dO : CAP;
      if (dO == 0) continue;
      const float* __restrict__ ndr = nd + r * N_NODES;
      const uint4* __restrict__ bkt = (const uint4*)(slots_out + (size_t)rn * CAP);
      float coef = 0.f;
      const int nq = (dO + 3) >> 2;
      for (int bi = 0; bi < nq; ++bi) {
        const uint4 q = bkt[bi];
        const int e = bi * 4;
        coef += ndr[q.x];
        if (e + 1 < dO) coef += ndr[q.y];
        if (e + 2 < dO) coef += ndr[q.z];
        if (e + 3 < dO) coef += ndr[q.w];
      }
      const float w = coef * ns[rn];
#pragma unroll
      for (int k = 0; k < 8; ++k) acc[r][k] = fmaf(w, hf[k], acc[r][k]);
    }
  }
  const float inv = 1.0f / (float)N_NODES;
  const int t = threadIdx.x;
#pragma unroll
  for (int r = 0; r < NREL; ++r) {
    __syncthreads();
#pragma unroll
    for (int k = 0; k < 8; ++k) sh[sub][flane * 8 + k] = acc[r][k];
    __syncthreads();
    if (t < 128) {
      float s = 0.f;
#pragma unroll
      for (int j = 0; j < 16; ++j) s += sh[j][t];
      atomicAdd(&mv[r * HID + t], s * inv);
    }
  }
}

// ---------------- final: out_c = sum_rk mv[rk]*u[rk][c] + bias2@Wc + bc ----------------
__global__ __launch_bounds__(256) void k_final(const float* __restrict__ mv,
                                               const float* __restrict__ u,
                                               const float* __restrict__ bias2,
                                               const float* __restrict__ Wc,
                                               const float* __restrict__ bc,
                                               float* __restrict__ out) {
  __shared__ float r0[256], r1[256];
  const int t = threadIdx.x;
  float s0 = 0.f, s1 = 0.f;
  for (int rk = t; rk < NREL * HID; rk += 256) {
    const float m = mv[rk];
    s0 = fmaf(m, u[rk * 2], s0);
    s1 = fmaf(m, u[rk * 2 + 1], s1);
  }
  r0[t] = s0; r1[t] = s1;
  __syncthreads();
  for (int off = 128; off > 0; off >>= 1) {
    if (t < off) { r0[t] += r0[t + off]; r1[t] += r1[t + off]; }
    __syncthreads();
  }
  if (t == 0) {
    float t0 = bc[0], t1 = bc[1];
    for (int j = 0; j < HID; ++j) {
      const float b = bias2[j];
      t0 = fmaf(b, Wc[j * 2], t0);
      t1 = fmaf(b, Wc[j * 2 + 1], t1);
    }
    out[0] = r0[0] + t0;
    out[1] = r1[0] + t1;
  }
}

extern "C" void kernel_launch(void* const* d_in, const int* in_sizes, int n_in,
                              void* d_out, int out_size, void* d_ws, size_t ws_size,
                              hipStream_t stream) {
  (void)in_sizes; (void)n_in; (void)out_size; (void)ws_size;
  const float* x   = (const float*)d_in[0];
  const int* esrc  = (const int*)d_in[1];
  const int* edst  = (const int*)d_in[2];
  const float* W1  = (const float*)d_in[3];
  const float* b1  = (const float*)d_in[4];
  const float* W2  = (const float*)d_in[5];
  const float* b2  = (const float*)d_in[6];
  const float* Wc  = (const float*)d_in[7];
  const float* bc  = (const float*)d_in[8];
  float* out = (float*)d_out;

  char* p = (char*)d_ws;
  size_t off = 0;
  auto take = [&](size_t bytes) -> void* {
    void* q = p + off;
    off += (bytes + 255) & ~(size_t)255;
    return q;
  };
  // ---- zeroed region (contiguous, zeroed every call) ----
  int*   cursor_in  = (int*)take((size_t)RN * 4);
  int*   cursor_out = (int*)take((size_t)RN * 4);
  float* mv         = (float*)take((size_t)NREL * HID * 4);
  const size_t zero_bytes = off;
  // ---- non-zeroed region ----
  float* ns       = (float*)take((size_t)RN * 4);
  float* nd       = (float*)take((size_t)RN * 4);
  int*   csr_off  = (int*)  take((size_t)RN * 4);
  int4*  meta     = (int4*) take((size_t)RN * 16);
  int*   blockSums= (int*)  take((size_t)NREL * NB_SCAN * 4 + 256);
  unsigned int* slots_in  = (unsigned int*)take((size_t)RN * CAP * 4);  // 57.6 MB
  unsigned int* slots_out = (unsigned int*)take((size_t)RN * CAP * 4);  // 57.6 MB
  int2*  csr_ew   = (int2*) take((size_t)NREL * PADCAP * 8);            // 33.6 MB
  unsigned short* W1T = (unsigned short*)take((size_t)NREL * FDIM * HID * 2);
  float* bias1    = (float*)take(HID * 4);
  float* bias2    = (float*)take(HID * 4);
  float* u        = (float*)take((size_t)NREL * HID * 2 * 4);
  unsigned short* h  = (unsigned short*)take((size_t)N_NODES * FDIM * 2);
  unsigned short* xb = (unsigned short*)take((size_t)N_NODES * FDIM * 2);

  const int zero_q = (int)(zero_bytes / 16);
  k_zero<<<(zero_q + 255) / 256, 256, 0, stream>>>((uint4*)d_ws, zero_q);
  k_build<<<(RE / 4 + 255) / 256, 256, 0, stream>>>((const int4*)esrc, (const int4*)edst,
                                                    cursor_in, cursor_out,
                                                    slots_in, slots_out);
  k_prep<<<PREP_BLOCKS, 256, 0, stream>>>(cursor_in, cursor_out, ns, nd, x, xb,
                                          W1, b1, b2, W1T, bias1, bias2, W2, Wc, u);
  k_scan1<<<NREL * NB_SCAN, 1024, 0, stream>>>(cursor_in, csr_off, blockSums);
  k_scan2<<<1, 768, 0, stream>>>(blockSums);
  k_scan3<<<(RN + 255) / 256, 256, 0, stream>>>(csr_off, blockSums, cursor_in, meta);
  k_compact<<<(RN + 255) / 256, 256, 0, stream>>>(slots_in, meta, ns, csr_ew);
  k_layer1<<<(N_NODES + 63) / 64, 256, 0, stream>>>(xb, csr_ew, meta, W1T, bias1, h);
  k_mv<<<(N_NODES + 255) / 256, 256, 0, stream>>>(h, slots_out, cursor_out, ns, nd, mv);
  k_final<<<1, 256, 0, stream>>>(mv, u, bias2, Wc, bc, out);
}

// Round 8
// 590.940 us; speedup vs baseline: 2.0404x; 2.0404x over previous
//
#include <hip/hip_runtime.h>

#define N_NODES 100000
#define NREL 6
#define NEDGE 400000
#define FDIM 128
#define HID 128

constexpr int RN = NREL * N_NODES;   // 600000
constexpr int NBIN = 391;            // ceil(100000 / 256) node bins of 256
constexpr int BINCAP = 1280;         // staging entries per (rel,bin); mean 1024, +8 sigma
constexpr int CSRCAP = 2304;         // int2 CSR entries per (rel,bin); max 1280+768 padded
constexpr int CHUNK = 8192;          // edges per phase-1 block
constexpr int NCHUNK = (NEDGE + CHUNK - 1) / CHUNK;  // 49

// k_prep block-range dispatch
constexpr int NB_XC = (N_NODES * 32) / 256;           // 12500 (exact)
constexpr int NB_WC = (NREL * FDIM * HID) / 256;      // 384 (exact)
constexpr int PREP_BLOCKS = NB_XC + NB_WC + NREL + 1;

typedef __attribute__((ext_vector_type(8))) short short8;
typedef __attribute__((ext_vector_type(4))) float f32x4;

__device__ __forceinline__ unsigned short f2bf(float f) {
  union { float f; unsigned int u; } v; v.f = f;
  unsigned int u = v.u;
  unsigned int r = (u + 0x7FFFu + ((u >> 16) & 1u)) >> 16;
  return (unsigned short)r;
}
__device__ __forceinline__ float bflo(unsigned int w) {
  union { unsigned int u; float f; } v; v.u = w << 16; return v.f;
}
__device__ __forceinline__ float bfhi(unsigned int w) {
  union { unsigned int u; float f; } v; v.u = w & 0xffff0000u; return v.f;
}

// ---------------- zero (cursors + mv only; tiny) ----------------
__global__ void k_zero(unsigned int* __restrict__ p, int nwords) {
  int id = blockIdx.x * blockDim.x + threadIdx.x;
  if (id < nwords) p[id] = 0u;
}

// ---------------- phase 1: LDS-binned staging, both directions ----------------
__global__ __launch_bounds__(256) void k_phase1(
    const int* __restrict__ src, const int* __restrict__ dst,
    int* __restrict__ gCurIn, int* __restrict__ gCurOut,
    unsigned int* __restrict__ stIn, unsigned int* __restrict__ stOut) {
  __shared__ int hIn[NBIN], hOut[NBIN], bIn[NBIN], bOut[NBIN];
  const int r = blockIdx.x / NCHUNK;
  const int c = blockIdx.x % NCHUNK;
  const int t = threadIdx.x;
  for (int i = t; i < NBIN; i += 256) { hIn[i] = 0; hOut[i] = 0; }
  __syncthreads();
  const int base = c * CHUNK;
  const int lim = min(CHUNK, NEDGE - base);
  const int* __restrict__ sR = src + r * NEDGE + base;
  const int* __restrict__ dR = dst + r * NEDGE + base;
  for (int i = t; i < lim; i += 256) {
    atomicAdd(&hIn[dR[i] >> 8], 1);
    atomicAdd(&hOut[sR[i] >> 8], 1);
  }
  __syncthreads();
  for (int i = t; i < NBIN; i += 256) {
    bIn[i]  = atomicAdd(&gCurIn[r * NBIN + i], hIn[i]);
    bOut[i] = atomicAdd(&gCurOut[r * NBIN + i], hOut[i]);
    hIn[i] = 0; hOut[i] = 0;
  }
  __syncthreads();
  for (int i = t; i < lim; i += 256) {
    const int s = sR[i], d = dR[i];
    const int bi = d >> 8, bo = s >> 8;
    const int pi = bIn[bi] + atomicAdd(&hIn[bi], 1);
    const int po = bOut[bo] + atomicAdd(&hOut[bo], 1);
    // pack: bits 17..24 = node-local (0..255), bits 0..16 = other endpoint
    if (pi < BINCAP)
      stIn[(size_t)(r * NBIN + bi) * BINCAP + pi] = ((unsigned)(d & 255) << 17) | (unsigned)s;
    if (po < BINCAP)
      stOut[(size_t)(r * NBIN + bo) * BINCAP + po] = ((unsigned)(s & 255) << 17) | (unsigned)d;
  }
}

// ---------------- phase 2a: out-degree count -> ns ----------------
__global__ __launch_bounds__(256) void k_p2a(const unsigned int* __restrict__ stOut,
                                             const int* __restrict__ gCurOut,
                                             float* __restrict__ ns) {
  __shared__ int cnt[256];
  const int rb = blockIdx.x;
  const int r = rb / NBIN, b = rb % NBIN;
  const int t = threadIdx.x;
  cnt[t] = 0;
  __syncthreads();
  const int m = min(gCurOut[rb], BINCAP);
  const unsigned int* __restrict__ st = stOut + (size_t)rb * BINCAP;
  for (int i = t; i < m; i += 256) atomicAdd(&cnt[st[i] >> 17], 1);
  __syncthreads();
  const int n = b * 256 + t;
  if (n < N_NODES) ns[r * N_NODES + n] = cnt[t] > 0 ? rsqrtf((float)cnt[t]) : 0.f;
}

// ---------------- phase 2b: in-count + scan -> meta, nd, dense padded CSR ----------------
__global__ __launch_bounds__(256) void k_p2in(const unsigned int* __restrict__ stIn,
                                              const int* __restrict__ gCurIn,
                                              const float* __restrict__ ns,
                                              int4* __restrict__ meta,
                                              float* __restrict__ ndA,
                                              int2* __restrict__ csr) {
  __shared__ int cnt[256], offs[256];
  __shared__ int wsum[4];
  const int rb = blockIdx.x;
  const int r = rb / NBIN, b = rb % NBIN;
  const int t = threadIdx.x;
  cnt[t] = 0;
  __syncthreads();
  const int m = min(gCurIn[rb], BINCAP);
  const unsigned int* __restrict__ st = stIn + (size_t)rb * BINCAP;
  for (int i = t; i < m; i += 256) atomicAdd(&cnt[st[i] >> 17], 1);
  __syncthreads();
  // exclusive scan of quad-padded counts
  const int lane = t & 63, wid = t >> 6;
  const int pc = (cnt[t] + 3) & ~3;
  int sum = pc;
#pragma unroll
  for (int o = 1; o < 64; o <<= 1) {
    int y = __shfl_up(sum, o);
    if (lane >= o) sum += y;
  }
  if (lane == 63) wsum[wid] = sum;
  __syncthreads();
  int wadd = 0;
  for (int w = 0; w < wid; ++w) wadd += wsum[w];
  offs[t] = sum - pc + wadd;
  __syncthreads();
  const int n = b * 256 + t;
  const int binBase = rb * CSRCAP;
  if (n < N_NODES) {
    const int d = cnt[t];
    const float nd = d > 0 ? rsqrtf((float)d) : 0.f;
    meta[r * N_NODES + n] = make_int4(d, binBase + offs[t], __float_as_int(nd), 0);
    ndA[r * N_NODES + n] = nd;
    int2* __restrict__ c = csr + binBase + offs[t];
    for (int e = d; e < ((d + 3) & ~3); ++e) c[e] = make_int2(0, 0);  // zero pads
  }
  __syncthreads();
  cnt[t] = 0;  // reuse as scatter cursors
  __syncthreads();
  const float* __restrict__ nsr = ns + r * N_NODES;
  for (int i = t; i < m; i += 256) {
    const unsigned int v = st[i];
    const int local = v >> 17;
    const int s = v & 0x1FFFF;
    const int pos = offs[local] + atomicAdd(&cnt[local], 1);
    csr[binBase + pos] = make_int2(s, __float_as_int(nsr[s]));
  }
}

// ---------------- phase 2c: coef = sum nd[dst] over out-edges -> wmv = ns*coef ----------------
__global__ __launch_bounds__(256) void k_p2b(const unsigned int* __restrict__ stOut,
                                             const int* __restrict__ gCurOut,
                                             const float* __restrict__ ns,
                                             const float* __restrict__ ndA,
                                             float* __restrict__ wmv) {
  __shared__ float fc[256];
  const int rb = blockIdx.x;
  const int r = rb / NBIN, b = rb % NBIN;
  const int t = threadIdx.x;
  fc[t] = 0.f;
  __syncthreads();
  const int m = min(gCurOut[rb], BINCAP);
  const unsigned int* __restrict__ st = stOut + (size_t)rb * BINCAP;
  const float* __restrict__ ndr = ndA + r * N_NODES;
  for (int i = t; i < m; i += 256) {
    const unsigned int v = st[i];
    atomicAdd(&fc[v >> 17], ndr[v & 0x1FFFF]);
  }
  __syncthreads();
  const int n = b * 256 + t;
  if (n < N_NODES) {
    const int rn = r * N_NODES + n;
    wmv[rn] = fc[t] * ns[rn];
  }
}

// ---------------- fused prep: x->bf16 | W1 transpose | u | biases ----------------
__global__ __launch_bounds__(256) void k_prep(
    const float* __restrict__ x, unsigned short* __restrict__ xb,
    const float* __restrict__ W1, const float* __restrict__ b1,
    const float* __restrict__ b2,
    unsigned short* __restrict__ W1T, float* __restrict__ bias1,
    float* __restrict__ bias2,
    const float* __restrict__ W2, const float* __restrict__ Wc,
    float* __restrict__ u) {
  const int b = blockIdx.x;
  const int t = threadIdx.x;
  if (b < NB_XC) {
    const int id = b * 256 + t;
    const float4 v = ((const float4*)x)[id];
    ushort4 o;
    o.x = f2bf(v.x); o.y = f2bf(v.y); o.z = f2bf(v.z); o.w = f2bf(v.w);
    ((ushort4*)xb)[id] = o;
  } else if (b < NB_XC + NB_WC) {
    const int id = (b - NB_XC) * 256 + t;
    const int r = id >> 14;
    const int rem = id & 16383;
    const int j = rem >> 7;
    const int k = rem & 127;
    W1T[id] = f2bf(W1[r * 16384 + k * 128 + j]);
  } else if (b < NB_XC + NB_WC + NREL) {
    const int r = b - (NB_XC + NB_WC);
    const int k = t >> 1;
    const int c = t & 1;
    const float* __restrict__ row = W2 + r * (HID * HID) + k * HID;
    float s = 0.f;
#pragma unroll 8
    for (int j = 0; j < HID; ++j) s = fmaf(row[j], Wc[j * 2 + c], s);
    u[(r * HID + k) * 2 + c] = s;
  } else {
    if (t < HID) {
      float s1 = 0.f, s2 = 0.f;
      for (int r = 0; r < NREL; ++r) {
        s1 += b1[r * HID + t];
        s2 += b2[r * HID + t];
      }
      bias1[t] = s1;
      bias2[t] = s2;
    }
  }
}

// ---------------- fused layer-1: barrier-free waves, dense CSR, MFMA ----------------
__global__ __launch_bounds__(256, 6) void k_layer1(
    const unsigned short* __restrict__ xb,      // [N][128] bf16
    const int2* __restrict__ csr_ew,            // bin-region CSR {src, w}
    const int4* __restrict__ meta,              // [R][N] {d, absOff, nd_bits, -}
    const unsigned short* __restrict__ W1T,     // [R][128][128] bf16 (out, in)
    const float* __restrict__ bias1,
    unsigned short* __restrict__ h)             // [N][128] bf16
{
  __shared__ unsigned short zA[4][16][136];     // per-wave private slices
  const int tid = threadIdx.x;
  const int wave = tid >> 6;
  const int lane = tid & 63;
  const int sub = lane >> 4;
  const int flane = lane & 15;
  const int wnb = blockIdx.x * 64 + wave * 16;

  f32x4 acc[8];
#pragma unroll
  for (int t = 0; t < 8; ++t) acc[t] = (f32x4){0.f, 0.f, 0.f, 0.f};

  const int pn = wnb + flane;
  const bool pok = pn < N_NODES;
  const int pnc = pok ? pn : (N_NODES - 1);
  int4 mt = meta[pnc];
  if (!pok) { mt.x = 0; mt.z = 0; }

  for (int r = 0; r < NREL; ++r) {
#pragma unroll
    for (int pass = 0; pass < 4; ++pass) {
      const int row = pass * 4 + sub;
      const int d = __shfl(mt.x, row);
      const int o = __shfl(mt.y, row);
      const float nd = __int_as_float(__shfl(mt.z, row));
      const uint4* __restrict__ lst = (const uint4*)(csr_ew + o);
      const unsigned fo = (unsigned)(flane << 3);
      float b[8];
#pragma unroll
      for (int k = 0; k < 8; ++k) b[k] = 0.f;
      const int nb = (d + 3) >> 2;
      for (int bi = 0; bi < nb; ++bi) {
        const uint4 qa = lst[2 * bi];       // {s0,w0,s1,w1}
        const uint4 qb = lst[2 * bi + 1];   // {s2,w2,s3,w3}
        const float w0 = __uint_as_float(qa.y);
        const float w1 = __uint_as_float(qa.w);
        const float w2 = __uint_as_float(qb.y);
        const float w3 = __uint_as_float(qb.w);
        const uint4 v0 = *(const uint4*)(xb + ((size_t)qa.x << 7) + fo);
        const uint4 v1 = *(const uint4*)(xb + ((size_t)qa.z << 7) + fo);
        const uint4 v2 = *(const uint4*)(xb + ((size_t)qb.x << 7) + fo);
        const uint4 v3 = *(const uint4*)(xb + ((size_t)qb.z << 7) + fo);
#define ACC8(V, W) \
        b[0] = fmaf(bflo(V.x), W, b[0]); b[1] = fmaf(bfhi(V.x), W, b[1]); \
        b[2] = fmaf(bflo(V.y), W, b[2]); b[3] = fmaf(bfhi(V.y), W, b[3]); \
        b[4] = fmaf(bflo(V.z), W, b[4]); b[5] = fmaf(bfhi(V.z), W, b[5]); \
        b[6] = fmaf(bflo(V.w), W, b[6]); b[7] = fmaf(bfhi(V.w), W, b[7]);
        ACC8(v0, w0) ACC8(v1, w1) ACC8(v2, w2) ACC8(v3, w3)
#undef ACC8
      }
      uint4 pk;
      pk.x = (unsigned)f2bf(b[0] * nd) | ((unsigned)f2bf(b[1] * nd) << 16);
      pk.y = (unsigned)f2bf(b[2] * nd) | ((unsigned)f2bf(b[3] * nd) << 16);
      pk.z = (unsigned)f2bf(b[4] * nd) | ((unsigned)f2bf(b[5] * nd) << 16);
      pk.w = (unsigned)f2bf(b[6] * nd) | ((unsigned)f2bf(b[7] * nd) << 16);
      *(uint4*)(&zA[wave][row][flane * 8]) = pk;
    }
    int4 mtn = mt;
    if (r + 1 < NREL) {
      mtn = meta[(r + 1) * N_NODES + pnc];
      if (!pok) { mtn.x = 0; mtn.z = 0; }
    }
    const int m = lane & 15;
    const int qq = lane >> 4;
    const unsigned short* __restrict__ wr = W1T + r * (FDIM * HID);
#pragma unroll
    for (int kk = 0; kk < 4; ++kk) {
      const short8 af = *(const short8*)(&zA[wave][m][kk * 32 + qq * 8]);
#pragma unroll
      for (int t = 0; t < 8; ++t) {
        const short8 bfr = *(const short8*)(wr + (t * 16 + m) * 128 + kk * 32 + qq * 8);
        acc[t] = __builtin_amdgcn_mfma_f32_16x16x32_bf16(af, bfr, acc[t], 0, 0, 0);
      }
    }
    mt = mtn;
  }
  const int col = lane & 15;
  const int rq = (lane >> 4) * 4;
#pragma unroll
  for (int t = 0; t < 8; ++t) {
#pragma unroll
    for (int rr = 0; rr < 4; ++rr) {
      const int node = wnb + rq + rr;
      if (node < N_NODES) {
        const int f = t * 16 + col;
        float v = acc[t][rr] + bias1[f];
        v = fmaxf(v, 0.f);
        h[(size_t)node * FDIM + f] = f2bf(v);
      }
    }
  }
}

// ---------------- layer-2 folded: dense h stream with precomputed weights ----------------
__global__ __launch_bounds__(256) void k_mv(const unsigned short* __restrict__ h,
                                            const float* __restrict__ wmv,
                                            float* __restrict__ mv) {
  __shared__ float sh[16][136];
  const int sub = threadIdx.x >> 4;
  const int flane = threadIdx.x & 15;
  const unsigned fo = (unsigned)(flane << 3);
  float acc[NREL][8];
#pragma unroll
  for (int r = 0; r < NREL; ++r)
#pragma unroll
    for (int k = 0; k < 8; ++k) acc[r][k] = 0.f;
  const int nbase = blockIdx.x * 256 + sub * 16;
  for (int i = 0; i < 16; ++i) {
    const int n = nbase + i;
    if (n >= N_NODES) break;
    const uint4 hv = *(const uint4*)(h + ((size_t)n << 7) + fo);
    float hf[8];
    hf[0] = bflo(hv.x); hf[1] = bfhi(hv.x); hf[2] = bflo(hv.y); hf[3] = bfhi(hv.y);
    hf[4] = bflo(hv.z); hf[5] = bfhi(hv.z); hf[6] = bflo(hv.w); hf[7] = bfhi(hv.w);
#pragma unroll
    for (int r = 0; r < NREL; ++r) {
      const float w = wmv[r * N_NODES + n];
#pragma unroll
      for (int k = 0; k < 8; ++k) acc[r][k] = fmaf(w, hf[k], acc[r][k]);
    }
  }
  const float inv = 1.0f / (float)N_NODES;
  const int t = threadIdx.x;
#pragma unroll
  for (int r = 0; r < NREL; ++r) {
    __syncthreads();
#pragma unroll
    for (int k = 0; k < 8; ++k) sh[sub][flane * 8 + k] = acc[r][k];
    __syncthreads();
    if (t < 128) {
      float s = 0.f;
#pragma unroll
      for (int j = 0; j < 16; ++j) s += sh[j][t];
      atomicAdd(&mv[r * HID + t], s * inv);
    }
  }
}

// ---------------- final ----------------
__global__ __launch_bounds__(256) void k_final(const float* __restrict__ mv,
                                               const float* __restrict__ u,
                                               const float* __restrict__ bias2,
                                               const float* __restrict__ Wc,
                                               const float* __restrict__ bc,
                                               float* __restrict__ out) {
  __shared__ float r0[256], r1[256];
  const int t = threadIdx.x;
  float s0 = 0.f, s1 = 0.f;
  for (int rk = t; rk < NREL * HID; rk += 256) {
    const float m = mv[rk];
    s0 = fmaf(m, u[rk * 2], s0);
    s1 = fmaf(m, u[rk * 2 + 1], s1);
  }
  r0[t] = s0; r1[t] = s1;
  __syncthreads();
  for (int off = 128; off > 0; off >>= 1) {
    if (t < off) { r0[t] += r0[t + off]; r1[t] += r1[t + off]; }
    __syncthreads();
  }
  if (t == 0) {
    float t0 = bc[0], t1 = bc[1];
    for (int j = 0; j < HID; ++j) {
      const float b = bias2[j];
      t0 = fmaf(b, Wc[j * 2], t0);
      t1 = fmaf(b, Wc[j * 2 + 1], t1);
    }
    out[0] = r0[0] + t0;
    out[1] = r1[0] + t1;
  }
}

extern "C" void kernel_launch(void* const* d_in, const int* in_sizes, int n_in,
                              void* d_out, int out_size, void* d_ws, size_t ws_size,
                              hipStream_t stream) {
  (void)in_sizes; (void)n_in; (void)out_size; (void)ws_size;
  const float* x   = (const float*)d_in[0];
  const int* esrc  = (const int*)d_in[1];
  const int* edst  = (const int*)d_in[2];
  const float* W1  = (const float*)d_in[3];
  const float* b1  = (const float*)d_in[4];
  const float* W2  = (const float*)d_in[5];
  const float* b2  = (const float*)d_in[6];
  const float* Wc  = (const float*)d_in[7];
  const float* bc  = (const float*)d_in[8];
  float* out = (float*)d_out;

  char* p = (char*)d_ws;
  size_t off = 0;
  auto take = [&](size_t bytes) -> void* {
    void* q = p + off;
    off += (bytes + 255) & ~(size_t)255;
    return q;
  };
  // ---- zeroed region (cursors + mv; ~22 KB) ----
  int*   gCurIn  = (int*)take((size_t)NREL * NBIN * 4);
  int*   gCurOut = (int*)take((size_t)NREL * NBIN * 4);
  float* mv      = (float*)take((size_t)NREL * HID * 4);
  const size_t zero_bytes = off;
  // ---- non-zeroed region ----
  float* ns   = (float*)take((size_t)RN * 4);
  float* ndA  = (float*)take((size_t)RN * 4);
  float* wmv  = (float*)take((size_t)RN * 4);
  int4*  meta = (int4*)take((size_t)RN * 16);
  unsigned int* stIn  = (unsigned int*)take((size_t)NREL * NBIN * BINCAP * 4);  // 12 MB
  unsigned int* stOut = (unsigned int*)take((size_t)NREL * NBIN * BINCAP * 4);  // 12 MB
  int2* csr = (int2*)take((size_t)NREL * NBIN * CSRCAP * 8);                    // 43 MB
  unsigned short* W1T = (unsigned short*)take((size_t)NREL * FDIM * HID * 2);
  float* bias1 = (float*)take(HID * 4);
  float* bias2 = (float*)take(HID * 4);
  float* u     = (float*)take((size_t)NREL * HID * 2 * 4);
  unsigned short* h  = (unsigned short*)take((size_t)N_NODES * FDIM * 2);
  unsigned short* xb = (unsigned short*)take((size_t)N_NODES * FDIM * 2);

  const int zero_words = (int)(zero_bytes / 4);
  k_zero<<<(zero_words + 255) / 256, 256, 0, stream>>>((unsigned int*)d_ws, zero_words);
  k_phase1<<<NREL * NCHUNK, 256, 0, stream>>>(esrc, edst, gCurIn, gCurOut, stIn, stOut);
  k_p2a<<<NREL * NBIN, 256, 0, stream>>>(stOut, gCurOut, ns);
  k_p2in<<<NREL * NBIN, 256, 0, stream>>>(stIn, gCurIn, ns, meta, ndA, csr);
  k_p2b<<<NREL * NBIN, 256, 0, stream>>>(stOut, gCurOut, ns, ndA, wmv);
  k_prep<<<PREP_BLOCKS, 256, 0, stream>>>(x, xb, W1, b1, b2, W1T, bias1, bias2, W2, Wc, u);
  k_layer1<<<(N_NODES + 63) / 64, 256, 0, stream>>>(xb, csr, meta, W1T, bias1, h);
  k_mv<<<(N_NODES + 255) / 256, 256, 0, stream>>>(h, wmv, mv);
  k_final<<<1, 256, 0, stream>>>(mv, u, bias2, Wc, bc, out);
}